// Round 1
// baseline (254.906 us; speedup 1.0000x reference)
//
#include <hip/hip_runtime.h>

// RWKV-7 DPLR single-step decode: B=64, H=32, K=V=128, fp32.
// Per (b,h): s = a^T H0 ; t = (q*g)^T H0 ; alpha=q.b ; beta=q.k
//            o = t + alpha*s + beta*v ; Ht = diag(g)H0 + b s^T + k v^T
// Memory-bound streaming op: H read once into registers, Ht written once.
// v2: 512-thread blocks, 8 rows x 4 cols of H per thread (Hreg[8] = 32 VGPRs
//     instead of Hreg[16] = 64) -> target 8 waves/SIMD, no spill risk.
//     Ht written with nontemporal stores (write-only data; keep h0 in L3).

#define KD 128
#define VD 128
#define BH_TOTAL 2048   // B*H = 64*32
#define NGRP 16         // row groups per block
#define RPT 8           // rows per thread

typedef float f32x4 __attribute__((ext_vector_type(4)));

__global__ __launch_bounds__(512) void dplr_decode_t1_kernel(
    const float* __restrict__ q_,  const float* __restrict__ k_,
    const float* __restrict__ v_,  const float* __restrict__ a_,
    const float* __restrict__ b_,  const float* __restrict__ gk_,
    const float* __restrict__ h0_, float* __restrict__ out_)
{
    const int bh  = blockIdx.x;          // 0..2047  (b*H + h)
    const int tid = threadIdx.x;         // 0..511
    const int c4  = (tid & 31) * 4;      // column base, 0..124
    const int grp = tid >> 5;            // row group 0..15 (half-wave granularity)
    const int r0  = grp * RPT;           // row base

    const size_t vec_off = (size_t)bh * KD;
    const size_t h_off   = (size_t)bh * (KD * VD);

    __shared__ float qs[KD], ks[KD], bs[KD], as_[KD], gs[KD], qgs[KD], vs[VD];
    __shared__ float sred[NGRP][VD];
    __shared__ float tred[NGRP][VD];
    __shared__ float scomb[VD];
    __shared__ float red2[2];            // [0]=alpha, [1]=beta

    // ---- issue H loads early (consumed after first sync) ----
    float4 Hreg[RPT];
    const float* hp = h0_ + h_off + (size_t)r0 * VD + c4;
#pragma unroll
    for (int j = 0; j < RPT; ++j) {
        Hreg[j] = *(const float4*)(hp + (size_t)j * VD);
    }

    // v for my 4 columns (used in the Ht rank-1 update)
    const float4 v4 = *(const float4*)(v_ + vec_off + c4);

    // ---- stage small per-(b,h) vectors into LDS ----
    if (tid < KD) {
        float qq = q_[vec_off + tid];
        float gg = expf(gk_[vec_off + tid]);
        qs[tid]  = qq;
        ks[tid]  = k_[vec_off + tid];
        bs[tid]  = b_[vec_off + tid];
        as_[tid] = a_[vec_off + tid];
        gs[tid]  = gg;
        qgs[tid] = qq * gg;
        vs[tid]  = v_[vec_off + tid];
    }
    __syncthreads();

    // ---- alpha = q.b (wave 0), beta = q.k (wave 1) ----
    if (tid < 64) {
        float p = qs[tid] * bs[tid] + qs[tid + 64] * bs[tid + 64];
#pragma unroll
        for (int o = 32; o > 0; o >>= 1) p += __shfl_down(p, o, 64);
        if (tid == 0) red2[0] = p;
    } else if (tid < 128) {
        int l = tid - 64;
        float p = qs[l] * ks[l] + qs[l + 64] * ks[l + 64];
#pragma unroll
        for (int o = 32; o > 0; o >>= 1) p += __shfl_down(p, o, 64);
        if (l == 0) red2[1] = p;
    }

    // ---- partial s/t over my 8 rows (a[r], qg[r] are half-wave-uniform) ----
    float4 sp = make_float4(0.f, 0.f, 0.f, 0.f);
    float4 tp = make_float4(0.f, 0.f, 0.f, 0.f);
#pragma unroll
    for (int j = 0; j < RPT; ++j) {
        const float av = as_[r0 + j];
        const float qg = qgs[r0 + j];
        const float4 h = Hreg[j];
        sp.x += av * h.x; sp.y += av * h.y; sp.z += av * h.z; sp.w += av * h.w;
        tp.x += qg * h.x; tp.y += qg * h.y; tp.z += qg * h.z; tp.w += qg * h.w;
    }
    *(float4*)&sred[grp][c4] = sp;
    *(float4*)&tred[grp][c4] = tp;
    __syncthreads();

    // ---- combine partials; write o ----
    if (tid < VD) {
        float sc = 0.f, tc = 0.f;
#pragma unroll
        for (int g = 0; g < NGRP; ++g) { sc += sred[g][tid]; tc += tred[g][tid]; }
        scomb[tid] = sc;
        out_[(size_t)bh * VD + tid] = tc + red2[0] * sc + red2[1] * vs[tid];
    }
    __syncthreads();

    // ---- Ht = g*H + b s^T + k v^T, written from registers (nontemporal) ----
    const float4 s4 = *(const float4*)&scomb[c4];
    float* op = out_ + (size_t)BH_TOTAL * VD + h_off + (size_t)r0 * VD + c4;
#pragma unroll
    for (int j = 0; j < RPT; ++j) {
        const int r = r0 + j;
        const float gr = gs[r];
        const float br = bs[r];
        const float kr = ks[r];
        const float4 h = Hreg[j];
        f32x4 o4;
        o4.x = gr * h.x + br * s4.x + kr * v4.x;
        o4.y = gr * h.y + br * s4.y + kr * v4.y;
        o4.z = gr * h.z + br * s4.z + kr * v4.z;
        o4.w = gr * h.w + br * s4.w + kr * v4.w;
        __builtin_nontemporal_store(o4, (f32x4*)(op + (size_t)j * VD));
    }
}

extern "C" void kernel_launch(void* const* d_in, const int* in_sizes, int n_in,
                              void* d_out, int out_size, void* d_ws, size_t ws_size,
                              hipStream_t stream) {
    const float* q  = (const float*)d_in[0];
    const float* k  = (const float*)d_in[1];
    const float* v  = (const float*)d_in[2];
    const float* a  = (const float*)d_in[3];
    const float* b  = (const float*)d_in[4];
    const float* gk = (const float*)d_in[5];
    const float* h0 = (const float*)d_in[6];
    float* out = (float*)d_out;

    dplr_decode_t1_kernel<<<BH_TOTAL, 512, 0, stream>>>(q, k, v, a, b, gk, h0, out);
}

// Round 2
// 254.299 us; speedup vs baseline: 1.0024x; 1.0024x over previous
//
#include <hip/hip_runtime.h>

// RWKV-7 DPLR single-step decode: B=64, H=32, K=V=128, fp32.
// Per (b,h): s = a^T H0 ; t = (q*g)^T H0 ; alpha=q.b ; beta=q.k
//            o = t + alpha*s + beta*v ; Ht = diag(g)H0 + b s^T + k v^T
// v3: force H to be register-resident across both phases.
//     Round-1 evidence: VGPR_Count=32 -> compiler rematerialized the H
//     loads (read H twice, phase 2 latency-chained on L2). Fix:
//     __launch_bounds__(512,4) gives a 128-VGPR budget, and an
//     asm "+v" pin on each Hreg makes rematerialization illegal.
//     Also: 2 barriers instead of 3 (each thread combines its own s4).

#define KD 128
#define VD 128
#define BH_TOTAL 2048   // B*H = 64*32
#define NGRP 16         // row groups per block
#define RPT 8           // rows per thread

typedef float f32x4 __attribute__((ext_vector_type(4)));

__global__ __launch_bounds__(512, 4) void dplr_decode_t1_kernel(
    const float* __restrict__ q_,  const float* __restrict__ k_,
    const float* __restrict__ v_,  const float* __restrict__ a_,
    const float* __restrict__ b_,  const float* __restrict__ gk_,
    const float* __restrict__ h0_, float* __restrict__ out_)
{
    const int bh  = blockIdx.x;          // 0..2047  (b*H + h)
    const int tid = threadIdx.x;         // 0..511
    const int c4  = (tid & 31) * 4;      // column base, 0..124
    const int grp = tid >> 5;            // row group 0..15
    const int r0  = grp * RPT;           // row base

    const size_t vec_off = (size_t)bh * KD;
    const size_t h_off   = (size_t)bh * (KD * VD);

    __shared__ float qs[KD], ks[KD], bs[KD], as_[KD], gs[KD], qgs[KD], vs[VD];
    __shared__ float sred[NGRP][VD];
    __shared__ float tred[NGRP][VD];
    __shared__ float red2[2];            // [0]=alpha, [1]=beta

    // ---- issue H loads (consumed in both phases; pinned below) ----
    f32x4 Hreg[RPT];
    const float* hp = h0_ + h_off + (size_t)r0 * VD + c4;
#pragma unroll
    for (int j = 0; j < RPT; ++j) {
        Hreg[j] = *(const f32x4*)(hp + (size_t)j * VD);
    }

    // v for my 4 columns (used in the Ht rank-1 update)
    const f32x4 v4 = *(const f32x4*)(v_ + vec_off + c4);

    // ---- stage small per-(b,h) vectors into LDS ----
    if (tid < KD) {
        float qq = q_[vec_off + tid];
        float gg = expf(gk_[vec_off + tid]);
        qs[tid]  = qq;
        ks[tid]  = k_[vec_off + tid];
        bs[tid]  = b_[vec_off + tid];
        as_[tid] = a_[vec_off + tid];
        gs[tid]  = gg;
        qgs[tid] = qq * gg;
        vs[tid]  = v_[vec_off + tid];
    }

    // Pin H in registers: "+v" makes the value an asm output, so the
    // compiler cannot re-load it from memory for the second use.
#pragma unroll
    for (int j = 0; j < RPT; ++j) {
        asm volatile("" : "+v"(Hreg[j]));
    }
    __syncthreads();

    // ---- alpha = q.b (wave 0), beta = q.k (wave 1) ----
    if (tid < 64) {
        float p = qs[tid] * bs[tid] + qs[tid + 64] * bs[tid + 64];
#pragma unroll
        for (int o = 32; o > 0; o >>= 1) p += __shfl_down(p, o, 64);
        if (tid == 0) red2[0] = p;
    } else if (tid < 128) {
        int l = tid - 64;
        float p = qs[l] * ks[l] + qs[l + 64] * ks[l + 64];
#pragma unroll
        for (int o = 32; o > 0; o >>= 1) p += __shfl_down(p, o, 64);
        if (l == 0) red2[1] = p;
    }

    // ---- partial s/t over my 8 rows ----
    f32x4 sp = {0.f, 0.f, 0.f, 0.f};
    f32x4 tp = {0.f, 0.f, 0.f, 0.f};
#pragma unroll
    for (int j = 0; j < RPT; ++j) {
        const float av = as_[r0 + j];
        const float qg = qgs[r0 + j];
        const f32x4 h = Hreg[j];
        sp += av * h;
        tp += qg * h;
    }
    *(f32x4*)&sred[grp][c4] = sp;
    *(f32x4*)&tred[grp][c4] = tp;
    __syncthreads();

    // ---- every thread combines its own s4 (no third barrier) ----
    f32x4 s4 = {0.f, 0.f, 0.f, 0.f};
#pragma unroll
    for (int g = 0; g < NGRP; ++g) {
        s4 += *(const f32x4*)&sred[g][c4];
    }

    // ---- o written by first 128 threads (their own column = tid) ----
    if (tid < VD) {
        float sc = 0.f, tc = 0.f;
#pragma unroll
        for (int g = 0; g < NGRP; ++g) { sc += sred[g][tid]; tc += tred[g][tid]; }
        out_[(size_t)bh * VD + tid] = tc + red2[0] * sc + red2[1] * vs[tid];
    }

    // ---- Ht = g*H + b s^T + k v^T, straight from registers (nt stores) ----
    float* op = out_ + (size_t)BH_TOTAL * VD + h_off + (size_t)r0 * VD + c4;
#pragma unroll
    for (int j = 0; j < RPT; ++j) {
        const int r = r0 + j;
        const float gr = gs[r];
        const float br = bs[r];
        const float kr = ks[r];
        f32x4 o4 = gr * Hreg[j] + br * s4 + kr * v4;
        __builtin_nontemporal_store(o4, (f32x4*)(op + (size_t)j * VD));
    }
}

extern "C" void kernel_launch(void* const* d_in, const int* in_sizes, int n_in,
                              void* d_out, int out_size, void* d_ws, size_t ws_size,
                              hipStream_t stream) {
    const float* q  = (const float*)d_in[0];
    const float* k  = (const float*)d_in[1];
    const float* v  = (const float*)d_in[2];
    const float* a  = (const float*)d_in[3];
    const float* b  = (const float*)d_in[4];
    const float* gk = (const float*)d_in[5];
    const float* h0 = (const float*)d_in[6];
    float* out = (float*)d_out;

    dplr_decode_t1_kernel<<<BH_TOTAL, 512, 0, stream>>>(q, k, v, a, b, gk, h0, out);
}

// Round 3
// 251.576 us; speedup vs baseline: 1.0132x; 1.0108x over previous
//
#include <hip/hip_runtime.h>

// RWKV-7 DPLR single-step decode: B=64, H=32, K=V=128, fp32.
// v4: persistent pipelined blocks. Round-2 evidence: three different
// kernel structures all pinned at ~86us / 2.4 TB/s regardless of
// occupancy (30% vs 62%) -> phase-convoy + __syncthreads vmcnt(0)
// drain is the suspected limiter. This version streams 4 bh per block
// with double-buffered LDS vectors + double-buffered H registers, and
// uses raw s_barrier + lgkmcnt-only waits so global prefetch (next H
// tile + next vec tile) stays in flight across barriers.

#define KD 128
#define VD 128
#define BH_TOTAL 2048   // B*H
#define NGRP 16         // row groups per block
#define RPT 8           // rows per thread
#define GRID 512        // 2 blocks per CU
#define ITERS 4         // bh per block; GRID*ITERS == BH_TOTAL

typedef float f32x4 __attribute__((ext_vector_type(4)));

// LDS-only barrier: waits LDS ops, does NOT drain vmcnt -> global
// prefetch survives the barrier (m201/HipKittens pattern).
#define LDS_BARRIER()                                      \
    do {                                                   \
        asm volatile("s_waitcnt lgkmcnt(0)" ::: "memory"); \
        __builtin_amdgcn_s_barrier();                      \
        __builtin_amdgcn_sched_barrier(0);                 \
        asm volatile("" ::: "memory");                     \
    } while (0)

__global__ __launch_bounds__(512, 4) void dplr_decode_t1_kernel(
    const float* __restrict__ q_,  const float* __restrict__ k_,
    const float* __restrict__ v_,  const float* __restrict__ a_,
    const float* __restrict__ b_,  const float* __restrict__ gk_,
    const float* __restrict__ h0_, float* __restrict__ out_)
{
    const int tid = threadIdx.x;         // 0..511
    const int c4  = (tid & 31) * 4;      // column base, 0..124
    const int grp = tid >> 5;            // row group 0..15
    const int r0  = grp * RPT;           // row base
    const int bh0 = blockIdx.x * ITERS;  // 4 consecutive bh per block

    __shared__ float qs[2][KD], ks[2][KD], bs[2][KD], as_[2][KD],
                     gs[2][KD], qgs[2][KD], vs[2][KD];
    __shared__ float sred[NGRP][VD];
    __shared__ float tred[NGRP][VD];
    __shared__ float red2[2];            // [0]=alpha, [1]=beta

    f32x4 Ha[RPT], Hb[RPT];

    // ---- staging helpers (tid<128 handles the 6 small vectors) ----
    float sq = 0.f, sk = 0.f, sb = 0.f, sa = 0.f, sg = 0.f, sv = 0.f;

#define STAGE_LOAD(bh)                                   \
    do { if (tid < KD) {                                 \
        const size_t off = (size_t)(bh)*KD + tid;        \
        sq = q_[off];  sk = k_[off];  sb = b_[off];      \
        sa = a_[off];  sg = gk_[off]; sv = v_[off];      \
    } } while (0)

#define STAGE_WRITE(p)                                   \
    do { if (tid < KD) {                                 \
        const float gg = expf(sg);                       \
        qs[p][tid]  = sq;  ks[p][tid] = sk;              \
        bs[p][tid]  = sb;  as_[p][tid] = sa;             \
        gs[p][tid]  = gg;  qgs[p][tid] = sq * gg;        \
        vs[p][tid]  = sv;                                \
    } } while (0)

#define LOAD_H(H, bh)                                                     \
    do {                                                                  \
        const float* hp_ = h0_ + (size_t)(bh)*(KD*VD) + (size_t)r0*VD + c4; \
        _Pragma("unroll")                                                 \
        for (int j = 0; j < RPT; ++j)                                     \
            H[j] = *(const f32x4*)(hp_ + (size_t)j * VD);                 \
    } while (0)

    // ---- prologue: stage vec(bh0) + H(bh0) ----
    STAGE_LOAD(bh0);
    STAGE_WRITE(0);
    LOAD_H(Ha, bh0);
    LDS_BARRIER();                       // vec(0) visible; Ha in flight

#define ITER_BODY(i, HCUR, HNXT)                                              \
    do {                                                                      \
        const int p = (i) & 1;                                                \
        /* T14: issue next vec loads first (latency hides under compute) */   \
        if ((i) + 1 < ITERS) STAGE_LOAD(bh0 + (i) + 1);                       \
        /* alpha = q.b (wave 0), beta = q.k (wave 1) */                       \
        if (tid < 64) {                                                       \
            float pr = qs[p][tid]*bs[p][tid] + qs[p][tid+64]*bs[p][tid+64];   \
            _Pragma("unroll")                                                 \
            for (int o = 32; o > 0; o >>= 1) pr += __shfl_down(pr, o, 64);    \
            if (tid == 0) red2[0] = pr;                                       \
        } else if (tid < 128) {                                               \
            const int l = tid - 64;                                           \
            float pr = qs[p][l]*ks[p][l] + qs[p][l+64]*ks[p][l+64];           \
            _Pragma("unroll")                                                 \
            for (int o = 32; o > 0; o >>= 1) pr += __shfl_down(pr, o, 64);    \
            if (l == 0) red2[1] = pr;                                         \
        }                                                                     \
        /* partial s/t over my 8 rows */                                      \
        f32x4 sp = {0.f,0.f,0.f,0.f}, tp = {0.f,0.f,0.f,0.f};                 \
        _Pragma("unroll")                                                     \
        for (int j = 0; j < RPT; ++j) {                                       \
            const float av = as_[p][r0+j];                                    \
            const float qg = qgs[p][r0+j];                                    \
            sp += av * HCUR[j];                                               \
            tp += qg * HCUR[j];                                               \
        }                                                                     \
        *(f32x4*)&sred[grp][c4] = sp;                                         \
        *(f32x4*)&tred[grp][c4] = tp;                                         \
        /* prefetch next tile: vec regs->LDS(other buf), H->other reg buf */  \
        if ((i) + 1 < ITERS) {                                                \
            STAGE_WRITE(p ^ 1);                                               \
            LOAD_H(HNXT, bh0 + (i) + 1);                                      \
        }                                                                     \
        LDS_BARRIER();   /* sred/tred + staged vec visible; H in flight */    \
        /* combine s4; Ht stores first (start write drain), then o */         \
        f32x4 s4 = {0.f,0.f,0.f,0.f};                                         \
        _Pragma("unroll")                                                     \
        for (int g = 0; g < NGRP; ++g) s4 += *(const f32x4*)&sred[g][c4];     \
        const f32x4 v4 = *(const f32x4*)&vs[p][c4];                           \
        float* op = out_ + (size_t)BH_TOTAL * VD                              \
                  + (size_t)(bh0+(i))*(KD*VD) + (size_t)r0*VD + c4;           \
        _Pragma("unroll")                                                     \
        for (int j = 0; j < RPT; ++j) {                                       \
            const int r = r0 + j;                                             \
            f32x4 o4 = gs[p][r]*HCUR[j] + bs[p][r]*s4 + ks[p][r]*v4;          \
            __builtin_nontemporal_store(o4, (f32x4*)(op + (size_t)j*VD));     \
        }                                                                     \
        if (tid < VD) {                                                       \
            float sc = 0.f, tc = 0.f;                                         \
            _Pragma("unroll")                                                 \
            for (int g = 0; g < NGRP; ++g) { sc += sred[g][tid]; tc += tred[g][tid]; } \
            out_[(size_t)(bh0+(i))*VD + tid] = tc + red2[0]*sc + red2[1]*vs[p][tid];   \
        }                                                                     \
        LDS_BARRIER();   /* protects sred/tred/red2 reuse next iter */        \
    } while (0)

    ITER_BODY(0, Ha, Hb);
    ITER_BODY(1, Hb, Ha);
    ITER_BODY(2, Ha, Hb);
    ITER_BODY(3, Hb, Ha);

#undef ITER_BODY
#undef LOAD_H
#undef STAGE_WRITE
#undef STAGE_LOAD
}

extern "C" void kernel_launch(void* const* d_in, const int* in_sizes, int n_in,
                              void* d_out, int out_size, void* d_ws, size_t ws_size,
                              hipStream_t stream) {
    const float* q  = (const float*)d_in[0];
    const float* k  = (const float*)d_in[1];
    const float* v  = (const float*)d_in[2];
    const float* a  = (const float*)d_in[3];
    const float* b  = (const float*)d_in[4];
    const float* gk = (const float*)d_in[5];
    const float* h0 = (const float*)d_in[6];
    float* out = (float*)d_out;

    dplr_decode_t1_kernel<<<GRID, 512, 0, stream>>>(q, k, v, a, b, gk, h0, out);
}